// Round 12
// baseline (91.899 us; speedup 1.0000x reference)
//
#include <hip/hip_runtime.h>
#include <hip/hip_fp16.h>
#include <math.h>

typedef unsigned long long u64;

constexpr int B = 512, T = 512, C = 128, L = 64;
constexpr int BLANK = C - 1;      // 127
constexpr float INV_LN2 = 1.44269504088896f;
constexpr float LN2 = 0.69314718055995f;

// ---------------------------------------------------------------------------
// async global->LDS (LDS dest = uniform base + lane*size; global src per-lane)
// ---------------------------------------------------------------------------
typedef const __attribute__((address_space(1))) void* gas_p;
typedef __attribute__((address_space(3))) void* las_p;
__device__ __forceinline__ void gload_lds16(const void* g, void* l) {
  __builtin_amdgcn_global_load_lds((gas_p)g, (las_p)l, 16, 0, 0);
}
__device__ __forceinline__ void gload_lds4(const void* g, void* l) {
  __builtin_amdgcn_global_load_lds((gas_p)g, (las_p)l, 4, 0, 0);
}
// deterministic full drain of the vmem queue (single-wave blocks: no barrier)
#define WAIT_VM0() do { \
  asm volatile("s_waitcnt vmcnt(0)" ::: "memory"); \
  __builtin_amdgcn_sched_barrier(0); } while (0)

// ---------------------------------------------------------------------------
// DPP / lane helpers
// ---------------------------------------------------------------------------
__device__ __forceinline__ float dpp_shr1_f(float x, float old) {
  int r = __builtin_amdgcn_update_dpp(__float_as_int(old), __float_as_int(x),
                                      0x138, 0xf, 0xf, false);  // wave_shr:1
  return __int_as_float(r);
}
__device__ __forceinline__ int dpp_shr1_i(int x, int old) {
  return __builtin_amdgcn_update_dpp(old, x, 0x138, 0xf, 0xf, false);
}
__device__ __forceinline__ float scan_max64(float x) {
  const int NI = (int)0xff800000;  // -inf
  int t;
  t = __builtin_amdgcn_update_dpp(NI, __float_as_int(x), 0x111, 0xf, 0xf, false);
  x = fmaxf(x, __int_as_float(t));
  t = __builtin_amdgcn_update_dpp(NI, __float_as_int(x), 0x112, 0xf, 0xf, false);
  x = fmaxf(x, __int_as_float(t));
  t = __builtin_amdgcn_update_dpp(NI, __float_as_int(x), 0x114, 0xf, 0xf, false);
  x = fmaxf(x, __int_as_float(t));
  t = __builtin_amdgcn_update_dpp(NI, __float_as_int(x), 0x118, 0xf, 0xf, false);
  x = fmaxf(x, __int_as_float(t));
  t = __builtin_amdgcn_update_dpp(NI, __float_as_int(x), 0x142, 0xa, 0xf, false);
  x = fmaxf(x, __int_as_float(t));
  t = __builtin_amdgcn_update_dpp(NI, __float_as_int(x), 0x143, 0xc, 0xf, false);
  x = fmaxf(x, __int_as_float(t));
  return x;  // lane63 = wave max
}
__device__ __forceinline__ float scan_add64(float x) {
  int t;
  t = __builtin_amdgcn_update_dpp(0, __float_as_int(x), 0x111, 0xf, 0xf, false);
  x += __int_as_float(t);
  t = __builtin_amdgcn_update_dpp(0, __float_as_int(x), 0x112, 0xf, 0xf, false);
  x += __int_as_float(t);
  t = __builtin_amdgcn_update_dpp(0, __float_as_int(x), 0x114, 0xf, 0xf, false);
  x += __int_as_float(t);
  t = __builtin_amdgcn_update_dpp(0, __float_as_int(x), 0x118, 0xf, 0xf, false);
  x += __int_as_float(t);
  t = __builtin_amdgcn_update_dpp(0, __float_as_int(x), 0x142, 0xa, 0xf, false);
  x += __int_as_float(t);
  t = __builtin_amdgcn_update_dpp(0, __float_as_int(x), 0x143, 0xc, 0xf, false);
  x += __int_as_float(t);
  return x;  // lane63 = wave sum
}
__device__ __forceinline__ float readlane63(float x) {
  return __int_as_float(__builtin_amdgcn_readlane(__float_as_int(x), 63));
}

// ---------------------------------------------------------------------------
// K1: per-(b,t) row stats. Writes PROBABILITIES:
//   p_lab[b][t][j] f16 = softmax[labels[b,j]] (j-fast), p_blh[b][t] f16,
//   predc[b][t] u8 argmax, eqm[b][t] u64 = ballot(labels==pred) (Myers Peq).
// Grid: blockIdx = chunk*512 + b  (all chunks of sample b on XCD b%8).
// ---------------------------------------------------------------------------
__global__ __launch_bounds__(256) void rowstats_kernel(
    const float* __restrict__ logits, const int* __restrict__ labels,
    __half* __restrict__ p_lab, __half* __restrict__ p_blh,
    unsigned char* __restrict__ predc, u64* __restrict__ eqm) {
  int b = blockIdx.x & 511;
  int t0 = (blockIdx.x >> 9) << 6;
  int w = threadIdx.x >> 6;
  int lane = threadIdx.x & 63;
  int lab = labels[((size_t)b << 6) + lane];
  for (int i = 0; i < 16; ++i) {
    int t = t0 + w * 16 + i;
    const float* rp = logits + (size_t)(b * T + t) * C;
    float v1 = rp[lane];
    float v2 = rp[lane + 64];
    float m = readlane63(scan_max64(fmaxf(v1, v2)));
    unsigned long long b1 = __ballot(v1 == m);
    unsigned long long b2 = __ballot(v2 == m);
    int idx = b1 ? (__ffsll(b1) - 1) : (64 + __ffsll(b2) - 1);
    u64 eqmask = __ballot(lab == idx);
    float e1 = __builtin_amdgcn_exp2f((v1 - m) * INV_LN2);
    float e2 = __builtin_amdgcn_exp2f((v2 - m) * INV_LN2);
    float rs = __builtin_amdgcn_rcpf(readlane63(scan_add64(e1 + e2)));
    float p1 = e1 * rs;   // prob of class `lane`
    float p2 = e2 * rs;   // prob of class `lane+64`
    float g1 = __shfl(p1, lab & 63);
    float g2 = __shfl(p2, lab & 63);
    float gp = (lab < 64) ? g1 : g2;
    p_lab[((size_t)(b * T + t)) * 64 + lane] = __float2half(gp);
    if (lane == 63) p_blh[b * T + t] = __float2half(p2);  // class 127 = blank
    if (lane == 0) { predc[b * T + t] = (unsigned char)idx; eqm[b * T + t] = eqmask; }
  }
}

// ---------------------------------------------------------------------------
// CTC alpha step, probability domain with PER-LANE block-floating-point.
// Lane j holds {state 2j+1 = qO, state 2j+2 = qE} scaled by 2^m (m per-lane
// int). State 0 = scalar chain (q0, m0). Cross-lane terms re-scaled with one
// v_ldexp_f32 by dm = m_{j-1} - m_j. No transcendentals on the chain.
// ---------------------------------------------------------------------------
__device__ __forceinline__ void ctc_step_p(float pl, float pb, bool skip_ok,
                                           float& qE, float& qO, int& m,
                                           float& q0, int& m0) {
  float pE = dpp_shr1_f(qE, q0);     // neighbor qE (lane0 <- q0)
  float pO = dpp_shr1_f(qO, 0.0f);   // neighbor qO (lane0 <- none)
  int mN = dpp_shr1_i(m, m0);        // neighbor scale (lane0 <- m0)
  int dm = mN - m;
  float pEs = ldexpf(pE, dm);
  float pOs = ldexpf(pO, dm);
  float a3 = skip_ok ? pOs : 0.0f;
  float nO = (qO + pEs + a3) * pl;   // odd state 2j+1
  float nE = (qE + qO) * pb;         // even state 2j+2 (in-lane only)
  q0 *= pb;
  qE = nE; qO = nO;
}

// per-lane renorm (every 4 steps): exact power-of-2, dead lanes adopt the
// left neighbor's scale so frontier arrivals never flush.
__device__ __forceinline__ void renorm_q(float& qE, float& qO, int& m,
                                         float& q0, int& m0) {
  float mx = fmaxf(qE, qO);
  int mprev = dpp_shr1_i(m, m0);
  int e = (__float_as_int(mx) >> 23) & 0xff;
  bool dead = (mx == 0.0f);
  int sh = e - 127;
  qE = ldexpf(qE, -sh);
  qO = ldexpf(qO, -sh);
  m = dead ? mprev : (m + sh);
  int e0 = ((__float_as_int(q0) >> 23) & 0xff) - 127;
  q0 = ldexpf(q0, -e0);
  m0 += e0;
}

// Myers/Hyyrö bit-parallel Levenshtein step (lane = one sample; select-only).
__device__ __forceinline__ void ed_step(u64 eq, int cc, int shift, bool tok,
                                        u64& Pv, u64& Mv, int& score, int& prevc) {
  bool keep = (cc != BLANK) && (cc != prevc) && tok;
  u64 Xv = eq | Mv;
  u64 Xh = (((eq & Pv) + Pv) ^ Pv) | eq;
  u64 Ph = Mv | ~(Xh | Pv);
  u64 Mh = Pv & Xh;
  int d = (int)((Ph >> shift) & 1ULL) - (int)((Mh >> shift) & 1ULL);
  score += keep ? d : 0;
  Ph = (Ph << 1) | 1ULL;
  Mh <<= 1;
  u64 nPv = Mh | ~(Xv | Ph);
  u64 nMv = Ph & Xv;
  Pv = keep ? nPv : Pv;
  Mv = keep ? nMv : Mv;
  prevc = cc;
}

// ---------------------------------------------------------------------------
// K2 fused. Blocks [0,8): Myers edit distance (lane = sample). Blocks
// [8,8+B): CTC prob-domain BFP (wave = sample, 64-t chunks staged to LDS via
// async global_load_lds, double-buffered, full vmcnt(0) drain one compute
// phase after issue). LDS: max(2*8448, 2*18432) = 36864 B.
// ---------------------------------------------------------------------------
__global__ __launch_bounds__(64, 1) void dp_kernel(
    const __half* __restrict__ p_lab, const __half* __restrict__ p_blh,
    const unsigned char* __restrict__ predc, const u64* __restrict__ eqm,
    const int* __restrict__ labels, const int* __restrict__ label_len,
    const int* __restrict__ logit_len,
    float* __restrict__ loss_b, float* __restrict__ ler_b) {
  __shared__ char smem[36864];
  int lane = threadIdx.x;

  if (blockIdx.x >= 8) {
    // ---------------- CTC path ----------------
    int b = blockIdx.x - 8;
    int tl = logit_len[b];
    int ll = label_len[b];
    int lab = labels[((size_t)b << 6) + lane];
    int labp = __shfl_up(lab, 1);
    bool skip_ok = (lane > 0) && (lab != labp);
    const char* srcL = (const char*)(p_lab + (size_t)b * T * 64);
    const char* srcB = (const char*)(p_blh + (size_t)b * T);
    float qE = 0.0f, qO, q0;
    int m = 0, m0 = 0;

    if (tl == T) {
      // stage chunk c (64 t) into slot s: p_lab 8KB (8 issues) + p_bl (1)
      auto stage = [&](int c, int s) {
        char* Lb = smem + s * 8448;
#pragma unroll
        for (int k = 0; k < 8; ++k)
          gload_lds16(srcL + (size_t)c * 8192 + k * 1024 + lane * 16,
                      Lb + k * 1024);
        gload_lds4(srcB + (size_t)c * 128 + lane * 4, Lb + 8192);
      };
      stage(0, 0);
      WAIT_VM0();
      stage(1, 1);
      {  // chunk 0 (peeled for t=0 init)
        const __half* pl = (const __half*)(smem);
        const __half* pb = (const __half*)(smem + 8192);
        q0 = __half2float(pb[0]);                          // alpha[0](0)
        qO = (lane == 0) ? __half2float(pl[lane]) : 0.0f;  // alpha[1](0)
        for (int g = 0; g < 16; ++g) {
#pragma unroll
          for (int kk = 0; kk < 4; ++kk) {
            int k = g * 4 + kk;
            if (k == 0) continue;
            ctc_step_p(__half2float(pl[k * 64 + lane]), __half2float(pb[k]),
                       skip_ok, qE, qO, m, q0, m0);
          }
          renorm_q(qE, qO, m, q0, m0);
        }
      }
#pragma unroll 1
      for (int c = 1; c < 8; ++c) {
        int s = c & 1;
        WAIT_VM0();                       // chunk c (staged last phase) ready
        if (c < 7) stage(c + 1, s ^ 1);   // prefetch next into other slot
        const __half* pl = (const __half*)(smem + s * 8448);
        const __half* pb = (const __half*)(smem + s * 8448 + 8192);
        for (int g = 0; g < 16; ++g) {
#pragma unroll
          for (int kk = 0; kk < 4; ++kk) {
            int k = g * 4 + kk;
            ctc_step_p(__half2float(pl[k * 64 + lane]), __half2float(pb[k]),
                       skip_ok, qE, qO, m, q0, m0);
          }
          renorm_q(qE, qO, m, q0, m0);
        }
      }
    } else {
      // general fallback (not exercised by this input shape)
      const __half* pl = (const __half*)srcL;
      const __half* pb = (const __half*)srcB;
      q0 = __half2float(pb[0]);
      qO = (lane == 0) ? __half2float(pl[lane]) : 0.0f;
      for (int t = 1; t < tl; ++t) {
        ctc_step_p(__half2float(pl[(size_t)t * 64 + lane]), __half2float(pb[t]),
                   skip_ok, qE, qO, m, q0, m0);
        if ((t & 3) == 3) renorm_q(qE, qO, m, q0, m0);
      }
    }
    // alpha[2ll] = qE, alpha[2ll-1] = qO at lane ll-1, both scaled by 2^m.
    float e1 = __shfl(qE, ll - 1);
    float e2 = __shfl(qO, ll - 1);
    int msel = __shfl(m, ll - 1);
    if (lane == 0) {
      float r = (float)msel + __builtin_amdgcn_logf(e1 + e2);   // log2 total
      loss_b[b] = -r * LN2;
    }
  } else {
    // ---------------- Myers edit distance (lane = sample) ----------------
    int bb = (blockIdx.x << 6) + lane;
    int tl = logit_len[bb];
    int ll = label_len[bb];
    int shift = ll - 1;
    u64 Pv = ~0ULL, Mv = 0ULL;
    int score = ll;
    int prevc = 255;
    const char* eqB = (const char*)(eqm + (size_t)bb * T);   // per-lane base
    const char* pqB = (const char*)(predc + (size_t)bb * T); // per-lane base
    // stage chunk c (32 t) into slot s: eq 16 issues + pred 2 issues
    auto stage = [&](int c, int s) {
      char* Eb = smem + s * 18432;
#pragma unroll
      for (int k = 0; k < 16; ++k)
        gload_lds16(eqB + (size_t)c * 256 + k * 16, Eb + k * 1024);
#pragma unroll
      for (int k = 0; k < 2; ++k)
        gload_lds16(pqB + (size_t)c * 32 + k * 16, Eb + 16384 + k * 1024);
    };
    stage(0, 0);
    WAIT_VM0();
    stage(1, 1);
#pragma unroll 1
    for (int c = 0; c < 16; ++c) {
      int s = c & 1;
      if (c) {
        WAIT_VM0();                       // chunk c ready
        if (c < 15) stage(c + 1, s ^ 1);  // prefetch next
      }
      const u64* ep = (const u64*)(smem + s * 18432);
      const unsigned char* pp = (const unsigned char*)(smem + s * 18432 + 16384);
#pragma unroll
      for (int k = 0; k < 32; ++k) {
        u64 eq = ep[(k >> 1) * 128 + lane * 2 + (k & 1)];
        int cc = pp[(k >> 4) * 1024 + lane * 16 + (k & 15)];
        ed_step(eq, cc, shift, c * 32 + k < tl, Pv, Mv, score, prevc);
      }
    }
    ler_b[bb] = (float)score / (float)ll;
  }
}

// ---------------------------------------------------------------------------
// K3: deterministic final mean over B for loss and ler.
// ---------------------------------------------------------------------------
__global__ __launch_bounds__(512) void reduce_kernel(
    const float* __restrict__ loss_b, const float* __restrict__ ler_b,
    float* __restrict__ out) {
  __shared__ float sl[512];
  __shared__ float sr[512];
  int tid = threadIdx.x;
  sl[tid] = loss_b[tid];
  sr[tid] = ler_b[tid];
  __syncthreads();
  for (int off = 256; off; off >>= 1) {
    if (tid < off) { sl[tid] += sl[tid + off]; sr[tid] += sr[tid + off]; }
    __syncthreads();
  }
  if (tid == 0) {
    out[0] = sl[0] / (float)B;
    out[1] = sr[0] / (float)B;
  }
}

extern "C" void kernel_launch(void* const* d_in, const int* in_sizes, int n_in,
                              void* d_out, int out_size, void* d_ws, size_t ws_size,
                              hipStream_t stream) {
  const int*   labels    = (const int*)d_in[0];
  const float* logits    = (const float*)d_in[1];
  const int*   label_len = (const int*)d_in[2];
  const int*   logit_len = (const int*)d_in[3];
  float* out = (float*)d_out;

  char* ws = (char*)d_ws;
  const size_t OFF_BLH  = (size_t)B * T * 64 * 2;        // after 32MB p_lab
  const size_t OFF_EQM  = OFF_BLH + (size_t)B * T * 2;   // after 0.5MB p_blh
  const size_t OFF_PRED = OFF_EQM + (size_t)B * T * 8;   // after 2MB eqm
  const size_t OFF_RED  = OFF_PRED + (size_t)B * T;      // after 0.25MB predc
  __half* p_lab = (__half*)ws;
  __half* p_blh = (__half*)(ws + OFF_BLH);
  u64*    eqm   = (u64*)(ws + OFF_EQM);
  unsigned char* predc = (unsigned char*)(ws + OFF_PRED);
  float*  loss_b = (float*)(ws + OFF_RED);
  float*  ler_b  = loss_b + B;

  rowstats_kernel<<<B * (T / 64), 256, 0, stream>>>(logits, labels, p_lab,
                                                    p_blh, predc, eqm);
  dp_kernel<<<B + 8, 64, 0, stream>>>(p_lab, p_blh, predc, eqm, labels,
                                      label_len, logit_len, loss_b, ler_b);
  reduce_kernel<<<1, 512, 0, stream>>>(loss_b, ler_b, out);
}